// Round 11
// baseline (713.312 us; speedup 1.0000x reference)
//
#include <hip/hip_runtime.h>

#define F_IN 128
#define DIM_H 256
#define N_CLASSES 40
#define BN_EPS 1e-5f
#define M_PAD 50176

typedef short bf16x8 __attribute__((ext_vector_type(8)));
typedef float f32x4 __attribute__((ext_vector_type(4)));

__device__ __forceinline__ unsigned short f2bf(float f) {
    union { float f; unsigned u; } v; v.f = f;
    unsigned r = v.u + 0x7fff + ((v.u >> 16) & 1);  // RNE
    return (unsigned short)(r >> 16);
}
__device__ __forceinline__ float bf2f(unsigned short u) {
    union { unsigned u; float f; } v; v.u = ((unsigned)u) << 16;
    return v.f;
}
__device__ __forceinline__ float4 bf2f4(ushort4 u) {
    return make_float4(bf2f(u.x), bf2f(u.y), bf2f(u.z), bf2f(u.w));
}

// ---------------- Phase A: histogram of dst ----------------
__global__ void hist_kernel(const int* __restrict__ dst, int* __restrict__ hist, int nE) {
    int e = blockIdx.x * blockDim.x + threadIdx.x;
    if (e >= nE) return;
    atomicAdd(&hist[dst[e]], 1);
}

// ---------------- Phase B: scan ----------------
__global__ void scan_blocks_kernel(const int* __restrict__ hist,
                                   int* __restrict__ blockSums, int M) {
    __shared__ int lds[256];
    int t = threadIdx.x;
    int i = blockIdx.x * 256 + t;
    lds[t] = (i < M) ? hist[i] : 0;
    __syncthreads();
    for (int off = 128; off > 0; off >>= 1) {
        if (t < off) lds[t] += lds[t + off];
        __syncthreads();
    }
    if (t == 0) blockSums[blockIdx.x] = lds[0];
}

__global__ void scan_final_kernel(const int* __restrict__ hist,
                                  const int* __restrict__ blockSums,
                                  int* __restrict__ start, int M, int nE) {
    __shared__ int lds[256];
    int t = threadIdx.x;
    lds[t] = (t < blockIdx.x) ? blockSums[t] : 0;
    __syncthreads();
    for (int o = 128; o > 0; o >>= 1) {
        if (t < o) lds[t] += lds[t + o];
        __syncthreads();
    }
    int off = lds[0];
    __syncthreads();
    int i = blockIdx.x * 256 + t;
    int orig = (i < M) ? hist[i] : 0;
    lds[t] = orig;
    __syncthreads();
    for (int o = 1; o < 256; o <<= 1) {
        int v = (t >= o) ? lds[t - o] : 0;
        __syncthreads();
        lds[t] += v;
        __syncthreads();
    }
    if (i < M) start[i] = off + lds[t] - orig;
    if (blockIdx.x == 0 && t == 0) start[M] = nE;
}

// ---------------- Phase C: bucket-fill, packing (dstLocal<<16 | src) ----------------
// src < 50000 < 65536 fits in 16 bits; dstLocal = dst % 64 (gather tiles are 64-aligned).
__global__ void fill_kernel(const int* __restrict__ src, const int* __restrict__ dst,
                            const int* __restrict__ start, int* __restrict__ cursor,
                            int* __restrict__ order, int nE) {
    int e = blockIdx.x * blockDim.x + threadIdx.x;
    if (e >= nE) return;
    int d = dst[e];
    int pos = start[d] + atomicAdd(&cursor[d], 1);
    order[pos] = (src[e] & 0xFFFF) | ((d & 63) << 16);
}

// ---------------- prep: xb = bf16(x), weight transposes, hist+cursor zeroing ----------------
__global__ void prep_kernel(const float* __restrict__ x, unsigned short* __restrict__ xb,
                            const float* __restrict__ W1, const float* __restrict__ W2,
                            const float* __restrict__ Wl,
                            unsigned short* __restrict__ W1t,
                            unsigned short* __restrict__ W2t,
                            unsigned short* __restrict__ Wlt,
                            int* __restrict__ histz,   // hist + cursor (adjacent), 2*M ints
                            int XQ, int ZQ) {
    int idx = blockIdx.x * 256 + threadIdx.x;
    if (idx < XQ) {
        float4 v = ((const float4*)x)[idx];
        ushort4 o;
        o.x = f2bf(v.x); o.y = f2bf(v.y); o.z = f2bf(v.z); o.w = f2bf(v.w);
        ((ushort4*)xb)[idx] = o;
        return;
    }
    int j = idx - XQ;
    if (j < 32768) {                    // W1t: [n=256][k=128]
        int n = j >> 7, k = j & 127;
        W1t[j] = f2bf(W1[k * DIM_H + n]);
    } else if (j < 32768 + 65536) {     // W2t: [n=256][k=256]
        int i = j - 32768;
        int n = i >> 8, k = i & 255;
        W2t[i] = f2bf(W2[k * DIM_H + n]);
    } else if (j < 32768 + 65536 + 16384) {  // Wlt: [n=64][k=256]
        int i = j - 98304;
        int n = i >> 8, k = i & 255;
        Wlt[i] = f2bf((n < N_CLASSES) ? Wl[k * N_CLASSES + n] : 0.f);
    } else {
        int z = j - 114688;
        if (z >= 0 && z < ZQ) ((int4*)histz)[z] = make_int4(0, 0, 0, 0);
    }
}

// ---------------- BN reduce ----------------
__global__ void bn_reduce_kernel(const float* __restrict__ partials, int R,
                                 const float* __restrict__ gamma,
                                 const float* __restrict__ beta,
                                 float* __restrict__ scale,
                                 float* __restrict__ shift, int M) {
    __shared__ float ls[256], lss[256];
    int c = blockIdx.x, t = threadIdx.x;
    float s = 0.f, ss = 0.f;
    for (int r = t; r < R; r += 256) {
        s += partials[(long)r * 512 + c];
        ss += partials[(long)r * 512 + 256 + c];
    }
    ls[t] = s; lss[t] = ss;
    __syncthreads();
    for (int o = 128; o > 0; o >>= 1) {
        if (t < o) { ls[t] += ls[t + o]; lss[t] += lss[t + o]; }
        __syncthreads();
    }
    if (t == 0) {
        float inv = 1.0f / (float)M;
        float mean = ls[0] * inv;
        float var = lss[0] * inv - mean * mean;
        float sc = gamma[c] * rsqrtf(var + BN_EPS);
        scale[c] = sc;
        shift[c] = beta[c] - mean * sc;
    }
}

// ---------------- fused edge-parallel gather + GEMM1 + BN partials ----------------
// 64-row tile, 4 waves. Block's edges are CONTIGUOUS in order[] (sorted by dst):
// all 8 half-waves stream the edge list round-robin, accumulating into an LDS
// fp32 A-tile via ds_add_f32 (dstLocal packed in order's high bits).
// K-loop: A from LDS (fp32->bf16 cvt), B (W1t, 64 KB L2-hot) direct from global
// with register prefetch -> NO barriers in K-loop, no Bs buffer.
// LDS 33.8 KB (fp32 tile; h1-staging aliases it) -> 4 blocks/CU, single generation.
__global__ __launch_bounds__(256, 4) void gin_gemm1_kernel(
    const unsigned short* __restrict__ xb,
    const int* __restrict__ order, const int* __restrict__ start,
    const unsigned short* __restrict__ W1t, const float* __restrict__ b1,
    unsigned short* __restrict__ h1, float* __restrict__ partials, int M) {
    constexpr int S = F_IN / 32;   // 4
    constexpr int PF = 132;        // fp32 tile pitch (128 + 4)
    constexpr int PH = 264;        // h1 staging pitch (ushort)
    __shared__ __align__(16) float Af[64 * PF];            // 33792 B
    unsigned short* h1t = (unsigned short*)Af;             // alias (64*264 ush = 33792 B)

    int tid = threadIdx.x;
    int wave = tid >> 6, lane = tid & 63;
    int l15 = lane & 15, q = lane >> 4;
    int wn = wave;
    long row0 = (long)blockIdx.x * 64;

    // ---- init: Af[row][ch] = bf2f(xb[node][ch]) (self term), 0 for pad rows ----
    {
        int row = tid >> 2, seg = tid & 3;     // 32 channels per thread
        long node = row0 + row;
        float* dst = &Af[row * PF + seg * 32];
        if (node < M) {
            const unsigned short* srcp = xb + node * F_IN + seg * 32;
#pragma unroll
            for (int c = 0; c < 4; ++c) {
                ushort4 u = *(const ushort4*)(srcp + c * 8);
                ushort4 u2 = *(const ushort4*)(srcp + c * 8 + 4);
                float4 f0 = bf2f4(u), f1 = bf2f4(u2);
                *(float4*)(dst + c * 8) = f0;
                *(float4*)(dst + c * 8 + 4) = f1;
            }
        } else {
#pragma unroll
            for (int c = 0; c < 8; ++c)
                *(float4*)(dst + c * 4) = make_float4(0.f, 0.f, 0.f, 0.f);
        }
    }
    __syncthreads();

    // ---- edge-parallel gather: 8 half-waves stream contiguous edge range ----
    {
        int hw = tid >> 5, lane32 = tid & 31;
        int rend = (int)min(row0 + 64, (long)M);
        int estart = start[row0], eend = start[rend];
        const ushort4* xv = (const ushort4*)xb;
        int e = estart + hw;
        // 4-deep unroll: edges e, e+8, e+16, e+24 independent
        for (; e + 24 < eend; e += 32) {
            int o0 = order[e], o1 = order[e + 8], o2 = order[e + 16], o3 = order[e + 24];
            float4 v0 = bf2f4(xv[(size_t)(o0 & 0xFFFF) * 32 + lane32]);
            float4 v1 = bf2f4(xv[(size_t)(o1 & 0xFFFF) * 32 + lane32]);
            float4 v2 = bf2f4(xv[(size_t)(o2 & 0xFFFF) * 32 + lane32]);
            float4 v3 = bf2f4(xv[(size_t)(o3 & 0xFFFF) * 32 + lane32]);
            float* p0 = &Af[(o0 >> 16) * PF + lane32 * 4];
            float* p1 = &Af[(o1 >> 16) * PF + lane32 * 4];
            float* p2 = &Af[(o2 >> 16) * PF + lane32 * 4];
            float* p3 = &Af[(o3 >> 16) * PF + lane32 * 4];
            atomicAdd(p0 + 0, v0.x); atomicAdd(p0 + 1, v0.y); atomicAdd(p0 + 2, v0.z); atomicAdd(p0 + 3, v0.w);
            atomicAdd(p1 + 0, v1.x); atomicAdd(p1 + 1, v1.y); atomicAdd(p1 + 2, v1.z); atomicAdd(p1 + 3, v1.w);
            atomicAdd(p2 + 0, v2.x); atomicAdd(p2 + 1, v2.y); atomicAdd(p2 + 2, v2.z); atomicAdd(p2 + 3, v2.w);
            atomicAdd(p3 + 0, v3.x); atomicAdd(p3 + 1, v3.y); atomicAdd(p3 + 2, v3.z); atomicAdd(p3 + 3, v3.w);
        }
        for (; e < eend; e += 8) {
            int o0 = order[e];
            float4 v0 = bf2f4(xv[(size_t)(o0 & 0xFFFF) * 32 + lane32]);
            float* p0 = &Af[(o0 >> 16) * PF + lane32 * 4];
            atomicAdd(p0 + 0, v0.x); atomicAdd(p0 + 1, v0.y);
            atomicAdd(p0 + 2, v0.z); atomicAdd(p0 + 3, v0.w);
        }
    }
    __syncthreads();

    // ---- K-loop: A from LDS fp32 (cvt to bf16), B direct from global (reg prefetch) ----
    f32x4 acc[4][4] = {};
    bf16x8 bcur[4], bnxt[4];
#pragma unroll
    for (int nt = 0; nt < 4; ++nt)
        bcur[nt] = *(const bf16x8*)(W1t + (wn * 64 + nt * 16 + l15) * F_IN + q * 8);
#pragma unroll
    for (int s = 0; s < S; ++s) {
        if (s + 1 < S) {
#pragma unroll
            for (int nt = 0; nt < 4; ++nt)
                bnxt[nt] = *(const bf16x8*)(W1t + (wn * 64 + nt * 16 + l15) * F_IN + (s + 1) * 32 + q * 8);
        }
        bf16x8 af[4];
#pragma unroll
        for (int mt = 0; mt < 4; ++mt) {
            const float* ap = &Af[(mt * 16 + l15) * PF + s * 32 + q * 8];
            float4 lo = *(const float4*)ap;
            float4 hi = *(const float4*)(ap + 4);
            bf16x8 a;
            a[0] = (short)f2bf(lo.x); a[1] = (short)f2bf(lo.y);
            a[2] = (short)f2bf(lo.z); a[3] = (short)f2bf(lo.w);
            a[4] = (short)f2bf(hi.x); a[5] = (short)f2bf(hi.y);
            a[6] = (short)f2bf(hi.z); a[7] = (short)f2bf(hi.w);
            af[mt] = a;
        }
#pragma unroll
        for (int mt = 0; mt < 4; ++mt)
#pragma unroll
            for (int nt = 0; nt < 4; ++nt)
                acc[mt][nt] = __builtin_amdgcn_mfma_f32_16x16x32_bf16(
                    af[mt], bcur[nt], acc[mt][nt], 0, 0, 0);
#pragma unroll
        for (int nt = 0; nt < 4; ++nt) bcur[nt] = bnxt[nt];
    }
    __syncthreads();  // Af reads complete before h1t alias writes

    // ---- Epilogue: BN partials + staged h1 tile ----
#pragma unroll
    for (int nt = 0; nt < 4; ++nt) {
        int col = wn * 64 + nt * 16 + l15;
        float b = b1[col];
        float s = 0.f, ss = 0.f;
#pragma unroll
        for (int mt = 0; mt < 4; ++mt) {
#pragma unroll
            for (int r = 0; r < 4; ++r) {
                long row = row0 + mt * 16 + q * 4 + r;
                float v = acc[mt][nt][r] + b;
                if (row < M) { s += v; ss += v * v; }
                h1t[(mt * 16 + q * 4 + r) * PH + col] = f2bf(v);
            }
        }
        s += __shfl_xor(s, 16, 64);  s += __shfl_xor(s, 32, 64);
        ss += __shfl_xor(ss, 16, 64); ss += __shfl_xor(ss, 32, 64);
        if (lane < 16) {
            partials[(long)blockIdx.x * 512 + col] = s;
            partials[(long)blockIdx.x * 512 + 256 + col] = ss;
        }
    }
    __syncthreads();
    {   // contiguous stores: thread t -> row t>>2, 64-col segment (t&3)*64
        int srow = tid >> 2, scol = (tid & 3) * 64;
        unsigned short* dst = h1 + (row0 + srow) * DIM_H + scol;
        const unsigned short* srcp = &h1t[srow * PH + scol];
#pragma unroll
        for (int j = 0; j < 8; ++j)
            *(bf16x8*)(dst + j * 8) = *(const bf16x8*)(srcp + j * 8);
    }
}

// ---------------- fused GEMM2 + GEMM3, 128x256 tile, 512 threads (unchanged R10) ----------------
__global__ __launch_bounds__(512, 4) void gemm23_kernel(
    const unsigned short* __restrict__ h1, const unsigned short* __restrict__ W2t,
    const float* __restrict__ b2,
    const float* __restrict__ scale, const float* __restrict__ shift,
    const unsigned short* __restrict__ Wlt, const float* __restrict__ blin,
    float* __restrict__ out, int M) {
    constexpr int S = 8;
    constexpr int PA = 40, PB = 40, PH = 264;
    constexpr int STAGE = 128 * PA + 256 * PB;
    __shared__ __align__(16) unsigned short lds[128 * PH];
    unsigned short* h2t = lds;

    int tid = threadIdx.x;
    int wave = tid >> 6, lane = tid & 63;
    int wm = wave >> 2, wn = wave & 3;
    int l15 = lane & 15, q = lane >> 4;
    long row0 = (long)blockIdx.x * 128;

    int am = tid >> 2, ac = tid & 3;
    bf16x8 ar, br[2];
    auto loadAB = [&](int s) {
        ar = *(const bf16x8*)(h1 + (row0 + am) * DIM_H + s * 32 + ac * 8);
#pragma unroll
        for (int i = 0; i < 2; ++i) {
            int ch = tid + i * 512;
            int m = ch >> 2, c = ch & 3;
            br[i] = *(const bf16x8*)(W2t + m * DIM_H + s * 32 + c * 8);
        }
    };
    auto writeAB = [&](int s, int buf) {
        unsigned short* As = lds + buf * STAGE;
        unsigned short* Bs = As + 128 * PA;
        {
            int kb = s * 32 + ac * 8;
            float4 sc0 = *(const float4*)(scale + kb);
            float4 sc1 = *(const float4*)(scale + kb + 4);
            float4 sh0 = *(const float4*)(shift + kb);
            float4 sh1 = *(const float4*)(shift + kb + 4);
            float scv[8] = {sc0.x, sc0.y, sc0.z, sc0.w, sc1.x, sc1.y, sc1.z, sc1.w};
            float shv[8] = {sh0.x, sh0.y, sh0.z, sh0.w, sh1.x, sh1.y, sh1.z, sh1.w};
            bf16x8 v = ar;
#pragma unroll
            for (int j = 0; j < 8; ++j) {
                float f = bf2f((unsigned short)v[j]);
                f = fmaxf(f * scv[j] + shv[j], 0.f);
                v[j] = (short)f2bf(f);
            }
            *(bf16x8*)(&As[am * PA + ac * 8]) = v;
        }
#pragma unroll
        for (int i = 0; i < 2; ++i) {
            int ch = tid + i * 512;
            int m = ch >> 2, c = ch & 3;
            *(bf16x8*)(&Bs[m * PB + c * 8]) = br[i];
        }
    };

    f32x4 acc[4][4] = {};
    loadAB(0);
    writeAB(0, 0);
#pragma unroll
    for (int s = 0; s < S; ++s) {
        if (s + 1 < S) loadAB(s + 1);
        __syncthreads();
        const unsigned short* As = lds + (s & 1) * STAGE;
        const unsigned short* Bs = As + 128 * PA;
        bf16x8 af[4], bfr[4];
#pragma unroll
        for (int mt = 0; mt < 4; ++mt)
            af[mt] = *(const bf16x8*)(&As[(wm * 64 + mt * 16 + l15) * PA + q * 8]);
#pragma unroll
        for (int nt = 0; nt < 4; ++nt)
            bfr[nt] = *(const bf16x8*)(&Bs[(wn * 64 + nt * 16 + l15) * PB + q * 8]);
#pragma unroll
        for (int mt = 0; mt < 4; ++mt)
#pragma unroll
            for (int nt = 0; nt < 4; ++nt)
                acc[mt][nt] = __builtin_amdgcn_mfma_f32_16x16x32_bf16(
                    af[mt], bfr[nt], acc[mt][nt], 0, 0, 0);
        if (s + 1 < S) writeAB(s + 1, (s + 1) & 1);
    }
    __syncthreads();

#pragma unroll
    for (int nt = 0; nt < 4; ++nt) {
        int colL = wn * 64 + nt * 16 + l15;
        float b = b2[colL];
#pragma unroll
        for (int mt = 0; mt < 4; ++mt)
#pragma unroll
            for (int r = 0; r < 4; ++r) {
                int rowL = wm * 64 + mt * 16 + q * 4 + r;
                h2t[rowL * PH + colL] = f2bf(fmaxf(acc[mt][nt][r] + b, 0.f));
            }
    }
    __syncthreads();

    f32x4 acc3[3] = {};
#pragma unroll
    for (int s = 0; s < 8; ++s) {
        bf16x8 a3 = *(const bf16x8*)(&h2t[(wave * 16 + l15) * PH + s * 32 + q * 8]);
#pragma unroll
        for (int nt = 0; nt < 3; ++nt) {
            bf16x8 b3 = *(const bf16x8*)(Wlt + (nt * 16 + l15) * 256 + s * 32 + q * 8);
            acc3[nt] = __builtin_amdgcn_mfma_f32_16x16x32_bf16(a3, b3, acc3[nt], 0, 0, 0);
        }
    }
#pragma unroll
    for (int nt = 0; nt < 3; ++nt) {
        int col = nt * 16 + l15;
        if (col < N_CLASSES) {
            float b = blin[col];
#pragma unroll
            for (int r = 0; r < 4; ++r) {
                long row = row0 + wave * 16 + q * 4 + r;
                if (row < M) out[row * N_CLASSES + col] = acc3[nt][r] + b;
            }
        }
    }
}

extern "C" void kernel_launch(void* const* d_in, const int* in_sizes, int n_in,
                              void* d_out, int out_size, void* d_ws, size_t ws_size,
                              hipStream_t stream) {
    const float* x     = (const float*)d_in[0];
    const int*   ei    = (const int*)d_in[1];
    const float* W1    = (const float*)d_in[2];
    const float* b1    = (const float*)d_in[3];
    const float* gamma = (const float*)d_in[4];
    const float* beta  = (const float*)d_in[5];
    const float* W2    = (const float*)d_in[6];
    const float* b2    = (const float*)d_in[7];
    const float* Wlin  = (const float*)d_in[8];
    const float* blin  = (const float*)d_in[9];
    float* out = (float*)d_out;

    int M  = in_sizes[0] / F_IN;  // 50000
    int nE = in_sizes[1] / 2;     // 600000
    const int* srcIdx = ei;
    const int* dstIdx = ei + nE;
    int nB = (M + 255) / 256;     // 196
    int gy1 = (M + 63) / 64;      // 782
    int gy23 = (M + 127) / 128;   // 391
    int XQ = M * 32;
    int ZQ = 2 * M / 4;

    unsigned short* h1bf  = (unsigned short*)d_ws;                     // M_PAD*256
    unsigned short* xb    = h1bf + (size_t)M_PAD * DIM_H;              // M_PAD*128
    unsigned short* W1t   = xb + (size_t)M_PAD * F_IN;                 // 256*128
    unsigned short* W2t   = W1t + DIM_H * F_IN;                        // 256*256
    unsigned short* Wlt   = W2t + DIM_H * DIM_H;                       // 64*256
    float*          partials = (float*)(Wlt + 64 * DIM_H);             // gy1*512
    float*          scale = partials + (size_t)800 * 512;              // 256
    float*          shift = scale + DIM_H;                             // 256
    int*            hist  = (int*)(shift + DIM_H);                     // M
    int*            cursor= hist + M;                                  // M (adjacent)
    int*            start = cursor + M;                                // M+1
    int*            blockSums = start + (M + 1);                       // 256
    int*            order = blockSums + 256;                           // nE

    int tB = 256;
    prep_kernel<<<(XQ + 114688 + ZQ + 255) / 256, 256, 0, stream>>>(
        x, xb, W1, W2, Wlin, W1t, W2t, Wlt, hist, XQ, ZQ);
    hist_kernel<<<(nE + tB - 1) / tB, tB, 0, stream>>>(dstIdx, hist, nE);
    scan_blocks_kernel<<<nB, 256, 0, stream>>>(hist, blockSums, M);
    scan_final_kernel<<<nB, 256, 0, stream>>>(hist, blockSums, start, M, nE);
    fill_kernel<<<(nE + tB - 1) / tB, tB, 0, stream>>>(srcIdx, dstIdx, start, cursor, order, nE);

    gin_gemm1_kernel<<<gy1, 256, 0, stream>>>(xb, order, start, W1t, b1, h1bf, partials, M);
    bn_reduce_kernel<<<DIM_H, 256, 0, stream>>>(partials, gy1, gamma, beta, scale, shift, M);
    gemm23_kernel<<<gy23, 512, 0, stream>>>(h1bf, W2t, b2, scale, shift, Wlt, blin, out, M);
}

// Round 12
// 239.660 us; speedup vs baseline: 2.9763x; 2.9763x over previous
//
#include <hip/hip_runtime.h>

#define F_IN 128
#define DIM_H 256
#define N_CLASSES 40
#define BN_EPS 1e-5f
#define M_PAD 50176

typedef short bf16x8 __attribute__((ext_vector_type(8)));
typedef float f32x4 __attribute__((ext_vector_type(4)));

__device__ __forceinline__ unsigned short f2bf(float f) {
    union { float f; unsigned u; } v; v.f = f;
    unsigned r = v.u + 0x7fff + ((v.u >> 16) & 1);  // RNE
    return (unsigned short)(r >> 16);
}
__device__ __forceinline__ float bf2f(unsigned short u) {
    union { unsigned u; float f; } v; v.u = ((unsigned)u) << 16;
    return v.f;
}
__device__ __forceinline__ float4 bf2f4(ushort4 u) {
    return make_float4(bf2f(u.x), bf2f(u.y), bf2f(u.z), bf2f(u.w));
}

// ---------------- Phase A: histogram of dst ----------------
__global__ void hist_kernel(const int* __restrict__ dst, int* __restrict__ hist, int nE) {
    int e = blockIdx.x * blockDim.x + threadIdx.x;
    if (e >= nE) return;
    atomicAdd(&hist[dst[e]], 1);
}

// ---------------- Phase B: scan ----------------
__global__ void scan_blocks_kernel(const int* __restrict__ hist,
                                   int* __restrict__ blockSums, int M) {
    __shared__ int lds[256];
    int t = threadIdx.x;
    int i = blockIdx.x * 256 + t;
    lds[t] = (i < M) ? hist[i] : 0;
    __syncthreads();
    for (int off = 128; off > 0; off >>= 1) {
        if (t < off) lds[t] += lds[t + off];
        __syncthreads();
    }
    if (t == 0) blockSums[blockIdx.x] = lds[0];
}

__global__ void scan_final_kernel(const int* __restrict__ hist,
                                  const int* __restrict__ blockSums,
                                  int* __restrict__ start, int M, int nE) {
    __shared__ int lds[256];
    int t = threadIdx.x;
    lds[t] = (t < blockIdx.x) ? blockSums[t] : 0;
    __syncthreads();
    for (int o = 128; o > 0; o >>= 1) {
        if (t < o) lds[t] += lds[t + o];
        __syncthreads();
    }
    int off = lds[0];
    __syncthreads();
    int i = blockIdx.x * 256 + t;
    int orig = (i < M) ? hist[i] : 0;
    lds[t] = orig;
    __syncthreads();
    for (int o = 1; o < 256; o <<= 1) {
        int v = (t >= o) ? lds[t - o] : 0;
        __syncthreads();
        lds[t] += v;
        __syncthreads();
    }
    if (i < M) start[i] = off + lds[t] - orig;
    if (blockIdx.x == 0 && t == 0) start[M] = nE;
}

// ---------------- Phase C: bucket-fill src indices ----------------
__global__ void fill_kernel(const int* __restrict__ src, const int* __restrict__ dst,
                            const int* __restrict__ start, int* __restrict__ cursor,
                            int* __restrict__ order, int nE) {
    int e = blockIdx.x * blockDim.x + threadIdx.x;
    if (e >= nE) return;
    int d = dst[e];
    int pos = start[d] + atomicAdd(&cursor[d], 1);
    order[pos] = src[e];
}

// ---------------- prep: xb = bf16(x), weight transposes, hist+cursor zeroing ----------------
__global__ void prep_kernel(const float* __restrict__ x, unsigned short* __restrict__ xb,
                            const float* __restrict__ W1, const float* __restrict__ W2,
                            const float* __restrict__ Wl,
                            unsigned short* __restrict__ W1t,
                            unsigned short* __restrict__ W2t,
                            unsigned short* __restrict__ Wlt,
                            int* __restrict__ histz,   // hist + cursor (adjacent), 2*M ints
                            int XQ, int ZQ) {
    int idx = blockIdx.x * 256 + threadIdx.x;
    if (idx < XQ) {
        float4 v = ((const float4*)x)[idx];
        ushort4 o;
        o.x = f2bf(v.x); o.y = f2bf(v.y); o.z = f2bf(v.z); o.w = f2bf(v.w);
        ((ushort4*)xb)[idx] = o;
        return;
    }
    int j = idx - XQ;
    if (j < 32768) {                    // W1t: [n=256][k=128]
        int n = j >> 7, k = j & 127;
        W1t[j] = f2bf(W1[k * DIM_H + n]);
    } else if (j < 32768 + 65536) {     // W2t: [n=256][k=256]
        int i = j - 32768;
        int n = i >> 8, k = i & 255;
        W2t[i] = f2bf(W2[k * DIM_H + n]);
    } else if (j < 32768 + 65536 + 16384) {  // Wlt: [n=64][k=256]
        int i = j - 98304;
        int n = i >> 8, k = i & 255;
        Wlt[i] = f2bf((n < N_CLASSES) ? Wl[k * N_CLASSES + n] : 0.f);
    } else {
        int z = j - 114688;
        if (z >= 0 && z < ZQ) ((int4*)histz)[z] = make_int4(0, 0, 0, 0);
    }
}

// ---------------- BN reduce ----------------
__global__ void bn_reduce_kernel(const float* __restrict__ partials, int R,
                                 const float* __restrict__ gamma,
                                 const float* __restrict__ beta,
                                 float* __restrict__ scale,
                                 float* __restrict__ shift, int M) {
    __shared__ float ls[256], lss[256];
    int c = blockIdx.x, t = threadIdx.x;
    float s = 0.f, ss = 0.f;
    for (int r = t; r < R; r += 256) {
        s += partials[(long)r * 512 + c];
        ss += partials[(long)r * 512 + 256 + c];
    }
    ls[t] = s; lss[t] = ss;
    __syncthreads();
    for (int o = 128; o > 0; o >>= 1) {
        if (t < o) { ls[t] += ls[t + o]; lss[t] += lss[t + o]; }
        __syncthreads();
    }
    if (t == 0) {
        float inv = 1.0f / (float)M;
        float mean = ls[0] * inv;
        float var = lss[0] * inv - mean * mean;
        float sc = gamma[c] * rsqrtf(var + BN_EPS);
        scale[c] = sc;
        shift[c] = beta[c] - mean * sc;
    }
}

// ---------------- fused gather + GEMM1 + BN partials (R10 structure, 8-deep MLP) ----------------
// 64-row tile, 4 waves. Half-wave per row, serial edge walk with 8 independent
// row-loads in flight. K-loop vs LDS-staged W1t (single-buffered, reg prefetch).
// Epilogue: BN partials + h1 staged through LDS for contiguous 16B stores.
// LDS 37.9 KB -> 4 blocks/CU (single generation at 782 blocks).
__global__ __launch_bounds__(256, 4) void gin_gemm1_kernel(
    const unsigned short* __restrict__ xb,
    const int* __restrict__ order, const int* __restrict__ start,
    const unsigned short* __restrict__ W1t, const float* __restrict__ b1,
    unsigned short* __restrict__ h1, float* __restrict__ partials, int M) {
    constexpr int K = F_IN, S = K / 32;
    constexpr int PA = 136;   // 128 + 8
    constexpr int PB = 40;    // 32 + 8
    constexpr int PH = 264;   // 256 + 8 (h1 staging alias)
    __shared__ __align__(16) unsigned short lds[64 * PA + 256 * PB];  // 37888 B
    unsigned short* At = lds;
    unsigned short* Bs = lds + 64 * PA;
    unsigned short* h1t = lds;  // 64*264 = 16896 ush <= 18944 (alias after K-loop)

    int tid = threadIdx.x;
    int wave = tid >> 6, lane = tid & 63;
    int l15 = lane & 15, q = lane >> 4;
    int wn = wave;
    long row0 = (long)blockIdx.x * 64;

    bf16x8 br[4];
    auto loadB = [&](int s) {
#pragma unroll
        for (int i = 0; i < 4; ++i) {
            int ch = tid + i * 256;
            int m = ch >> 2, c = ch & 3;
            br[i] = *(const bf16x8*)(W1t + m * K + s * 32 + c * 8);
        }
    };
    auto writeB = [&]() {
#pragma unroll
        for (int i = 0; i < 4; ++i) {
            int ch = tid + i * 256;
            int m = ch >> 2, c = ch & 3;
            *(bf16x8*)(&Bs[m * PB + c * 8]) = br[i];
        }
    };

    loadB(0);  // in flight during gather

    // ---- Phase 1: gather into At (bf16 self + neighbors, 8-deep load unroll) ----
    {
        int hw = tid >> 5, lane32 = tid & 31;
        const ushort4* xv = (const ushort4*)xb;
        for (int rr = 0; rr < 8; ++rr) {
            int r = rr * 8 + hw;
            long node = row0 + r;
            float4 a0 = make_float4(0.f, 0.f, 0.f, 0.f);
            float4 a1 = a0, a2 = a0, a3 = a0;
            if (node < M) {
                a0 = bf2f4(xv[node * 32 + lane32]);  // self term
                int e0 = start[node], e1 = start[node + 1];
                int e = e0;
                // 8 independent loads per iteration (MLP=8), 4 accumulators
                for (; e + 8 <= e1; e += 8) {
                    int s0 = order[e],     s1 = order[e + 1], s2 = order[e + 2], s3 = order[e + 3];
                    int s4 = order[e + 4], s5 = order[e + 5], s6 = order[e + 6], s7 = order[e + 7];
                    ushort4 u0 = xv[(size_t)s0 * 32 + lane32];
                    ushort4 u1 = xv[(size_t)s1 * 32 + lane32];
                    ushort4 u2 = xv[(size_t)s2 * 32 + lane32];
                    ushort4 u3 = xv[(size_t)s3 * 32 + lane32];
                    ushort4 u4 = xv[(size_t)s4 * 32 + lane32];
                    ushort4 u5 = xv[(size_t)s5 * 32 + lane32];
                    ushort4 u6 = xv[(size_t)s6 * 32 + lane32];
                    ushort4 u7 = xv[(size_t)s7 * 32 + lane32];
                    float4 v0 = bf2f4(u0), v1 = bf2f4(u1), v2 = bf2f4(u2), v3 = bf2f4(u3);
                    float4 v4 = bf2f4(u4), v5 = bf2f4(u5), v6 = bf2f4(u6), v7 = bf2f4(u7);
                    a0.x += v0.x; a0.y += v0.y; a0.z += v0.z; a0.w += v0.w;
                    a1.x += v1.x; a1.y += v1.y; a1.z += v1.z; a1.w += v1.w;
                    a2.x += v2.x; a2.y += v2.y; a2.z += v2.z; a2.w += v2.w;
                    a3.x += v3.x; a3.y += v3.y; a3.z += v3.z; a3.w += v3.w;
                    a0.x += v4.x; a0.y += v4.y; a0.z += v4.z; a0.w += v4.w;
                    a1.x += v5.x; a1.y += v5.y; a1.z += v5.z; a1.w += v5.w;
                    a2.x += v6.x; a2.y += v6.y; a2.z += v6.z; a2.w += v6.w;
                    a3.x += v7.x; a3.y += v7.y; a3.z += v7.z; a3.w += v7.w;
                }
                for (; e + 4 <= e1; e += 4) {
                    int s0 = order[e], s1 = order[e + 1], s2 = order[e + 2], s3 = order[e + 3];
                    float4 v0 = bf2f4(xv[(size_t)s0 * 32 + lane32]);
                    float4 v1 = bf2f4(xv[(size_t)s1 * 32 + lane32]);
                    float4 v2 = bf2f4(xv[(size_t)s2 * 32 + lane32]);
                    float4 v3 = bf2f4(xv[(size_t)s3 * 32 + lane32]);
                    a0.x += v0.x; a0.y += v0.y; a0.z += v0.z; a0.w += v0.w;
                    a1.x += v1.x; a1.y += v1.y; a1.z += v1.z; a1.w += v1.w;
                    a2.x += v2.x; a2.y += v2.y; a2.z += v2.z; a2.w += v2.w;
                    a3.x += v3.x; a3.y += v3.y; a3.z += v3.z; a3.w += v3.w;
                }
                for (; e < e1; ++e) {
                    float4 v = bf2f4(xv[(size_t)order[e] * 32 + lane32]);
                    a1.x += v.x; a1.y += v.y; a1.z += v.z; a1.w += v.w;
                }
            }
            float4 t;
            t.x = (a0.x + a1.x) + (a2.x + a3.x);
            t.y = (a0.y + a1.y) + (a2.y + a3.y);
            t.z = (a0.z + a1.z) + (a2.z + a3.z);
            t.w = (a0.w + a1.w) + (a2.w + a3.w);
            ushort4 o;
            o.x = f2bf(t.x); o.y = f2bf(t.y); o.z = f2bf(t.z); o.w = f2bf(t.w);
            *(ushort4*)(&At[r * PA + lane32 * 4]) = o;
        }
    }
    writeB();
    __syncthreads();

    // ---- Phase 2: K-loop ----
    f32x4 acc[4][4] = {};
#pragma unroll
    for (int s = 0; s < S; ++s) {
        if (s + 1 < S) loadB(s + 1);
        bf16x8 af[4], bfr[4];
#pragma unroll
        for (int mt = 0; mt < 4; ++mt)
            af[mt] = *(const bf16x8*)(&At[(mt * 16 + l15) * PA + s * 32 + q * 8]);
#pragma unroll
        for (int nt = 0; nt < 4; ++nt)
            bfr[nt] = *(const bf16x8*)(&Bs[(wn * 64 + nt * 16 + l15) * PB + q * 8]);
#pragma unroll
        for (int mt = 0; mt < 4; ++mt)
#pragma unroll
            for (int nt = 0; nt < 4; ++nt)
                acc[mt][nt] = __builtin_amdgcn_mfma_f32_16x16x32_bf16(
                    af[mt], bfr[nt], acc[mt][nt], 0, 0, 0);
        __syncthreads();
        if (s + 1 < S) { writeB(); __syncthreads(); }
    }
    // all waves past final barrier: At/Bs dead, safe to alias h1t

    // ---- Epilogue: BN partials (fp32, pre-round) + staged h1 tile ----
#pragma unroll
    for (int nt = 0; nt < 4; ++nt) {
        int col = wn * 64 + nt * 16 + l15;
        float b = b1[col];
        float s = 0.f, ss = 0.f;
#pragma unroll
        for (int mt = 0; mt < 4; ++mt) {
#pragma unroll
            for (int r = 0; r < 4; ++r) {
                long row = row0 + mt * 16 + q * 4 + r;
                float v = acc[mt][nt][r] + b;
                if (row < M) { s += v; ss += v * v; }
                h1t[(mt * 16 + q * 4 + r) * PH + col] = f2bf(v);
            }
        }
        s += __shfl_xor(s, 16, 64);  s += __shfl_xor(s, 32, 64);
        ss += __shfl_xor(ss, 16, 64); ss += __shfl_xor(ss, 32, 64);
        if (lane < 16) {
            partials[(long)blockIdx.x * 512 + col] = s;
            partials[(long)blockIdx.x * 512 + 256 + col] = ss;
        }
    }
    __syncthreads();
    {   // contiguous stores: thread t -> row t>>2, 64-col segment (t&3)*64
        int srow = tid >> 2, scol = (tid & 3) * 64;
        unsigned short* dst = h1 + (row0 + srow) * DIM_H + scol;
        const unsigned short* srcp = &h1t[srow * PH + scol];
#pragma unroll
        for (int j = 0; j < 8; ++j)
            *(bf16x8*)(dst + j * 8) = *(const bf16x8*)(srcp + j * 8);
    }
}

// ---------------- fused GEMM2 + GEMM3, 128x256 tile, 512 threads (unchanged R10) ----------------
__global__ __launch_bounds__(512, 4) void gemm23_kernel(
    const unsigned short* __restrict__ h1, const unsigned short* __restrict__ W2t,
    const float* __restrict__ b2,
    const float* __restrict__ scale, const float* __restrict__ shift,
    const unsigned short* __restrict__ Wlt, const float* __restrict__ blin,
    float* __restrict__ out, int M) {
    constexpr int S = 8;
    constexpr int PA = 40, PB = 40, PH = 264;
    constexpr int STAGE = 128 * PA + 256 * PB;
    __shared__ __align__(16) unsigned short lds[128 * PH];
    unsigned short* h2t = lds;

    int tid = threadIdx.x;
    int wave = tid >> 6, lane = tid & 63;
    int wm = wave >> 2, wn = wave & 3;
    int l15 = lane & 15, q = lane >> 4;
    long row0 = (long)blockIdx.x * 128;

    int am = tid >> 2, ac = tid & 3;
    bf16x8 ar, br[2];
    auto loadAB = [&](int s) {
        ar = *(const bf16x8*)(h1 + (row0 + am) * DIM_H + s * 32 + ac * 8);
#pragma unroll
        for (int i = 0; i < 2; ++i) {
            int ch = tid + i * 512;
            int m = ch >> 2, c = ch & 3;
            br[i] = *(const bf16x8*)(W2t + m * DIM_H + s * 32 + c * 8);
        }
    };
    auto writeAB = [&](int s, int buf) {
        unsigned short* As = lds + buf * STAGE;
        unsigned short* Bs = As + 128 * PA;
        {
            int kb = s * 32 + ac * 8;
            float4 sc0 = *(const float4*)(scale + kb);
            float4 sc1 = *(const float4*)(scale + kb + 4);
            float4 sh0 = *(const float4*)(shift + kb);
            float4 sh1 = *(const float4*)(shift + kb + 4);
            float scv[8] = {sc0.x, sc0.y, sc0.z, sc0.w, sc1.x, sc1.y, sc1.z, sc1.w};
            float shv[8] = {sh0.x, sh0.y, sh0.z, sh0.w, sh1.x, sh1.y, sh1.z, sh1.w};
            bf16x8 v = ar;
#pragma unroll
            for (int j = 0; j < 8; ++j) {
                float f = bf2f((unsigned short)v[j]);
                f = fmaxf(f * scv[j] + shv[j], 0.f);
                v[j] = (short)f2bf(f);
            }
            *(bf16x8*)(&As[am * PA + ac * 8]) = v;
        }
#pragma unroll
        for (int i = 0; i < 2; ++i) {
            int ch = tid + i * 512;
            int m = ch >> 2, c = ch & 3;
            *(bf16x8*)(&Bs[m * PB + c * 8]) = br[i];
        }
    };

    f32x4 acc[4][4] = {};
    loadAB(0);
    writeAB(0, 0);
#pragma unroll
    for (int s = 0; s < S; ++s) {
        if (s + 1 < S) loadAB(s + 1);
        __syncthreads();
        const unsigned short* As = lds + (s & 1) * STAGE;
        const unsigned short* Bs = As + 128 * PA;
        bf16x8 af[4], bfr[4];
#pragma unroll
        for (int mt = 0; mt < 4; ++mt)
            af[mt] = *(const bf16x8*)(&As[(wm * 64 + mt * 16 + l15) * PA + q * 8]);
#pragma unroll
        for (int nt = 0; nt < 4; ++nt)
            bfr[nt] = *(const bf16x8*)(&Bs[(wn * 64 + nt * 16 + l15) * PB + q * 8]);
#pragma unroll
        for (int mt = 0; mt < 4; ++mt)
#pragma unroll
            for (int nt = 0; nt < 4; ++nt)
                acc[mt][nt] = __builtin_amdgcn_mfma_f32_16x16x32_bf16(
                    af[mt], bfr[nt], acc[mt][nt], 0, 0, 0);
        if (s + 1 < S) writeAB(s + 1, (s + 1) & 1);
    }
    __syncthreads();

#pragma unroll
    for (int nt = 0; nt < 4; ++nt) {
        int colL = wn * 64 + nt * 16 + l15;
        float b = b2[colL];
#pragma unroll
        for (int mt = 0; mt < 4; ++mt)
#pragma unroll
            for (int r = 0; r < 4; ++r) {
                int rowL = wm * 64 + mt * 16 + q * 4 + r;
                h2t[rowL * PH + colL] = f2bf(fmaxf(acc[mt][nt][r] + b, 0.f));
            }
    }
    __syncthreads();

    f32x4 acc3[3] = {};
#pragma unroll
    for (int s = 0; s < 8; ++s) {
        bf16x8 a3 = *(const bf16x8*)(&h2t[(wave * 16 + l15) * PH + s * 32 + q * 8]);
#pragma unroll
        for (int nt = 0; nt < 3; ++nt) {
            bf16x8 b3 = *(const bf16x8*)(Wlt + (nt * 16 + l15) * 256 + s * 32 + q * 8);
            acc3[nt] = __builtin_amdgcn_mfma_f32_16x16x32_bf16(a3, b3, acc3[nt], 0, 0, 0);
        }
    }
#pragma unroll
    for (int nt = 0; nt < 3; ++nt) {
        int col = nt * 16 + l15;
        if (col < N_CLASSES) {
            float b = blin[col];
#pragma unroll
            for (int r = 0; r < 4; ++r) {
                long row = row0 + wave * 16 + q * 4 + r;
                if (row < M) out[row * N_CLASSES + col] = acc3[nt][r] + b;
            }
        }
    }
}

extern "C" void kernel_launch(void* const* d_in, const int* in_sizes, int n_in,
                              void* d_out, int out_size, void* d_ws, size_t ws_size,
                              hipStream_t stream) {
    const float* x     = (const float*)d_in[0];
    const int*   ei    = (const int*)d_in[1];
    const float* W1    = (const float*)d_in[2];
    const float* b1    = (const float*)d_in[3];
    const float* gamma = (const float*)d_in[4];
    const float* beta  = (const float*)d_in[5];
    const float* W2    = (const float*)d_in[6];
    const float* b2    = (const float*)d_in[7];
    const float* Wlin  = (const float*)d_in[8];
    const float* blin  = (const float*)d_in[9];
    float* out = (float*)d_out;

    int M  = in_sizes[0] / F_IN;  // 50000
    int nE = in_sizes[1] / 2;     // 600000
    const int* srcIdx = ei;
    const int* dstIdx = ei + nE;
    int nB = (M + 255) / 256;     // 196
    int gy1 = (M + 63) / 64;      // 782
    int gy23 = (M + 127) / 128;   // 391
    int XQ = M * 32;
    int ZQ = 2 * M / 4;

    unsigned short* h1bf  = (unsigned short*)d_ws;                     // M_PAD*256
    unsigned short* xb    = h1bf + (size_t)M_PAD * DIM_H;              // M_PAD*128
    unsigned short* W1t   = xb + (size_t)M_PAD * F_IN;                 // 256*128
    unsigned short* W2t   = W1t + DIM_H * F_IN;                        // 256*256
    unsigned short* Wlt   = W2t + DIM_H * DIM_H;                       // 64*256
    float*          partials = (float*)(Wlt + 64 * DIM_H);             // gy1*512
    float*          scale = partials + (size_t)800 * 512;              // 256
    float*          shift = scale + DIM_H;                             // 256
    int*            hist  = (int*)(shift + DIM_H);                     // M
    int*            cursor= hist + M;                                  // M (adjacent)
    int*            start = cursor + M;                                // M+1
    int*            blockSums = start + (M + 1);                       // 256
    int*            order = blockSums + 256;                           // nE

    int tB = 256;
    prep_kernel<<<(XQ + 114688 + ZQ + 255) / 256, 256, 0, stream>>>(
        x, xb, W1, W2, Wlin, W1t, W2t, Wlt, hist, XQ, ZQ);
    hist_kernel<<<(nE + tB - 1) / tB, tB, 0, stream>>>(dstIdx, hist, nE);
    scan_blocks_kernel<<<nB, 256, 0, stream>>>(hist, blockSums, M);
    scan_final_kernel<<<nB, 256, 0, stream>>>(hist, blockSums, start, M, nE);
    fill_kernel<<<(nE + tB - 1) / tB, tB, 0, stream>>>(srcIdx, dstIdx, start, cursor, order, nE);

    gin_gemm1_kernel<<<gy1, 256, 0, stream>>>(xb, order, start, W1t, b1, h1bf, partials, M);
    bn_reduce_kernel<<<DIM_H, 256, 0, stream>>>(partials, gy1, gamma, beta, scale, shift, M);
    gemm23_kernel<<<gy23, 512, 0, stream>>>(h1bf, W2t, b2, scale, shift, Wlt, blin, out, M);
}

// Round 13
// 233.403 us; speedup vs baseline: 3.0561x; 1.0268x over previous
//
#include <hip/hip_runtime.h>

#define F_IN 128
#define DIM_H 256
#define N_CLASSES 40
#define BN_EPS 1e-5f
#define M_PAD 50176

typedef short bf16x8 __attribute__((ext_vector_type(8)));
typedef float f32x4 __attribute__((ext_vector_type(4)));

__device__ __forceinline__ unsigned short f2bf(float f) {
    union { float f; unsigned u; } v; v.f = f;
    unsigned r = v.u + 0x7fff + ((v.u >> 16) & 1);  // RNE
    return (unsigned short)(r >> 16);
}
__device__ __forceinline__ float bf2f(unsigned short u) {
    union { unsigned u; float f; } v; v.u = ((unsigned)u) << 16;
    return v.f;
}
__device__ __forceinline__ float4 bf2f4(ushort4 u) {
    return make_float4(bf2f(u.x), bf2f(u.y), bf2f(u.z), bf2f(u.w));
}

// ---------------- Phase A: histogram of dst ----------------
__global__ void hist_kernel(const int* __restrict__ dst, int* __restrict__ hist, int nE) {
    int e = blockIdx.x * blockDim.x + threadIdx.x;
    if (e >= nE) return;
    atomicAdd(&hist[dst[e]], 1);
}

// ---------------- Phase B: scan ----------------
__global__ void scan_blocks_kernel(const int* __restrict__ hist,
                                   int* __restrict__ blockSums, int M) {
    __shared__ int lds[256];
    int t = threadIdx.x;
    int i = blockIdx.x * 256 + t;
    lds[t] = (i < M) ? hist[i] : 0;
    __syncthreads();
    for (int off = 128; off > 0; off >>= 1) {
        if (t < off) lds[t] += lds[t + off];
        __syncthreads();
    }
    if (t == 0) blockSums[blockIdx.x] = lds[0];
}

__global__ void scan_final_kernel(const int* __restrict__ hist,
                                  const int* __restrict__ blockSums,
                                  int* __restrict__ start, int M, int nE) {
    __shared__ int lds[256];
    int t = threadIdx.x;
    lds[t] = (t < blockIdx.x) ? blockSums[t] : 0;
    __syncthreads();
    for (int o = 128; o > 0; o >>= 1) {
        if (t < o) lds[t] += lds[t + o];
        __syncthreads();
    }
    int off = lds[0];
    __syncthreads();
    int i = blockIdx.x * 256 + t;
    int orig = (i < M) ? hist[i] : 0;
    lds[t] = orig;
    __syncthreads();
    for (int o = 1; o < 256; o <<= 1) {
        int v = (t >= o) ? lds[t - o] : 0;
        __syncthreads();
        lds[t] += v;
        __syncthreads();
    }
    if (i < M) start[i] = off + lds[t] - orig;
    if (blockIdx.x == 0 && t == 0) start[M] = nE;
}

// ---------------- Phase C: bucket-fill src indices ----------------
__global__ void fill_kernel(const int* __restrict__ src, const int* __restrict__ dst,
                            const int* __restrict__ start, int* __restrict__ cursor,
                            int* __restrict__ order, int nE) {
    int e = blockIdx.x * blockDim.x + threadIdx.x;
    if (e >= nE) return;
    int d = dst[e];
    int pos = start[d] + atomicAdd(&cursor[d], 1);
    order[pos] = src[e];
}

// ---------------- prep: xb = bf16(x), weight transposes, hist+cursor zeroing ----------------
__global__ void prep_kernel(const float* __restrict__ x, unsigned short* __restrict__ xb,
                            const float* __restrict__ W1, const float* __restrict__ W2,
                            const float* __restrict__ Wl,
                            unsigned short* __restrict__ W1t,
                            unsigned short* __restrict__ W2t,
                            unsigned short* __restrict__ Wlt,
                            int* __restrict__ histz, int XQ, int ZQ) {
    int idx = blockIdx.x * 256 + threadIdx.x;
    if (idx < XQ) {
        float4 v = ((const float4*)x)[idx];
        ushort4 o;
        o.x = f2bf(v.x); o.y = f2bf(v.y); o.z = f2bf(v.z); o.w = f2bf(v.w);
        ((ushort4*)xb)[idx] = o;
        return;
    }
    int j = idx - XQ;
    if (j < 32768) {                    // W1t: [n=256][k=128]
        int n = j >> 7, k = j & 127;
        W1t[j] = f2bf(W1[k * DIM_H + n]);
    } else if (j < 32768 + 65536) {     // W2t: [n=256][k=256]
        int i = j - 32768;
        int n = i >> 8, k = i & 255;
        W2t[i] = f2bf(W2[k * DIM_H + n]);
    } else if (j < 32768 + 65536 + 16384) {  // Wlt: [n=64][k=256]
        int i = j - 98304;
        int n = i >> 8, k = i & 255;
        Wlt[i] = f2bf((n < N_CLASSES) ? Wl[k * N_CLASSES + n] : 0.f);
    } else {
        int z = j - 114688;
        if (z >= 0 && z < ZQ) ((int4*)histz)[z] = make_int4(0, 0, 0, 0);
    }
}

// ---------------- BN reduce ----------------
__global__ void bn_reduce_kernel(const float* __restrict__ partials, int R,
                                 const float* __restrict__ gamma,
                                 const float* __restrict__ beta,
                                 float* __restrict__ scale,
                                 float* __restrict__ shift, int M) {
    __shared__ float ls[256], lss[256];
    int c = blockIdx.x, t = threadIdx.x;
    float s = 0.f, ss = 0.f;
    for (int r = t; r < R; r += 256) {
        s += partials[(long)r * 512 + c];
        ss += partials[(long)r * 512 + 256 + c];
    }
    ls[t] = s; lss[t] = ss;
    __syncthreads();
    for (int o = 128; o > 0; o >>= 1) {
        if (t < o) { ls[t] += ls[t + o]; lss[t] += lss[t + o]; }
        __syncthreads();
    }
    if (t == 0) {
        float inv = 1.0f / (float)M;
        float mean = ls[0] * inv;
        float var = lss[0] * inv - mean * mean;
        float sc = gamma[c] * rsqrtf(var + BN_EPS);
        scale[c] = sc;
        shift[c] = beta[c] - mean * sc;
    }
}

// ---------------- standalone gather: A1 = bf16(x + agg) ----------------
// One half-wave per row, 8-deep independent loads. No LDS, tiny VGPR count
// -> 8 waves/SIMD (32 waves/CU): 2x the concurrent requests of the fused version.
__global__ __launch_bounds__(256) void gather_kernel(
    const unsigned short* __restrict__ xb,
    const int* __restrict__ order, const int* __restrict__ start,
    unsigned short* __restrict__ A1, int M) {
    int node = blockIdx.x * 8 + (threadIdx.x >> 5);
    if (node >= M) return;
    int lane32 = threadIdx.x & 31;
    const ushort4* xv = (const ushort4*)xb;
    float4 a0 = bf2f4(xv[(size_t)node * 32 + lane32]);  // self term
    float4 a1 = make_float4(0.f, 0.f, 0.f, 0.f);
    float4 a2 = a1, a3 = a1;
    int e0 = start[node], e1 = start[node + 1];
    int e = e0;
    for (; e + 8 <= e1; e += 8) {
        int s0 = order[e],     s1 = order[e + 1], s2 = order[e + 2], s3 = order[e + 3];
        int s4 = order[e + 4], s5 = order[e + 5], s6 = order[e + 6], s7 = order[e + 7];
        ushort4 u0 = xv[(size_t)s0 * 32 + lane32];
        ushort4 u1 = xv[(size_t)s1 * 32 + lane32];
        ushort4 u2 = xv[(size_t)s2 * 32 + lane32];
        ushort4 u3 = xv[(size_t)s3 * 32 + lane32];
        ushort4 u4 = xv[(size_t)s4 * 32 + lane32];
        ushort4 u5 = xv[(size_t)s5 * 32 + lane32];
        ushort4 u6 = xv[(size_t)s6 * 32 + lane32];
        ushort4 u7 = xv[(size_t)s7 * 32 + lane32];
        float4 v0 = bf2f4(u0), v1 = bf2f4(u1), v2 = bf2f4(u2), v3 = bf2f4(u3);
        float4 v4 = bf2f4(u4), v5 = bf2f4(u5), v6 = bf2f4(u6), v7 = bf2f4(u7);
        a0.x += v0.x; a0.y += v0.y; a0.z += v0.z; a0.w += v0.w;
        a1.x += v1.x; a1.y += v1.y; a1.z += v1.z; a1.w += v1.w;
        a2.x += v2.x; a2.y += v2.y; a2.z += v2.z; a2.w += v2.w;
        a3.x += v3.x; a3.y += v3.y; a3.z += v3.z; a3.w += v3.w;
        a0.x += v4.x; a0.y += v4.y; a0.z += v4.z; a0.w += v4.w;
        a1.x += v5.x; a1.y += v5.y; a1.z += v5.z; a1.w += v5.w;
        a2.x += v6.x; a2.y += v6.y; a2.z += v6.z; a2.w += v6.w;
        a3.x += v7.x; a3.y += v7.y; a3.z += v7.z; a3.w += v7.w;
    }
    for (; e + 4 <= e1; e += 4) {
        int s0 = order[e], s1 = order[e + 1], s2 = order[e + 2], s3 = order[e + 3];
        float4 v0 = bf2f4(xv[(size_t)s0 * 32 + lane32]);
        float4 v1 = bf2f4(xv[(size_t)s1 * 32 + lane32]);
        float4 v2 = bf2f4(xv[(size_t)s2 * 32 + lane32]);
        float4 v3 = bf2f4(xv[(size_t)s3 * 32 + lane32]);
        a0.x += v0.x; a0.y += v0.y; a0.z += v0.z; a0.w += v0.w;
        a1.x += v1.x; a1.y += v1.y; a1.z += v1.z; a1.w += v1.w;
        a2.x += v2.x; a2.y += v2.y; a2.z += v2.z; a2.w += v2.w;
        a3.x += v3.x; a3.y += v3.y; a3.z += v3.z; a3.w += v3.w;
    }
    for (; e < e1; ++e) {
        float4 v = bf2f4(xv[(size_t)order[e] * 32 + lane32]);
        a1.x += v.x; a1.y += v.y; a1.z += v.z; a1.w += v.w;
    }
    float4 t;
    t.x = (a0.x + a1.x) + (a2.x + a3.x);
    t.y = (a0.y + a1.y) + (a2.y + a3.y);
    t.z = (a0.z + a1.z) + (a2.z + a3.z);
    t.w = (a0.w + a1.w) + (a2.w + a3.w);
    ushort4 o;
    o.x = f2bf(t.x); o.y = f2bf(t.y); o.z = f2bf(t.z); o.w = f2bf(t.w);
    ((ushort4*)A1)[(size_t)node * 32 + lane32] = o;
}

// ---------------- GEMM1: h1 = bf16(A1 @ W1 + b1) + BN partials ----------------
// 128x256 tile, 512 threads (2x4 waves), K=128 (4 steps), double-buffered staging.
// Epilogue: BN partials (2 rows/block) + h1 staged via LDS for contiguous stores.
__global__ __launch_bounds__(512, 4) void gemm1_kernel(
    const unsigned short* __restrict__ A1, const unsigned short* __restrict__ W1t,
    const float* __restrict__ b1, unsigned short* __restrict__ h1,
    float* __restrict__ partials, int M) {
    constexpr int S = 4;
    constexpr int PA = 40, PB = 40, PH = 264;
    constexpr int STAGE = 128 * PA + 256 * PB;        // 15360 ushorts per buffer
    __shared__ __align__(16) unsigned short lds[128 * PH];  // 67.6 KB >= 2*STAGE
    unsigned short* h1t = lds;

    int tid = threadIdx.x;
    int wave = tid >> 6, lane = tid & 63;
    int wm = wave >> 2, wn = wave & 3;
    int l15 = lane & 15, q = lane >> 4;
    long row0 = (long)blockIdx.x * 128;

    int am = tid >> 2, ac = tid & 3;
    bf16x8 ar, br[2];
    auto loadAB = [&](int s) {
        ar = *(const bf16x8*)(A1 + (row0 + am) * F_IN + s * 32 + ac * 8);
#pragma unroll
        for (int i = 0; i < 2; ++i) {
            int ch = tid + i * 512;
            int m = ch >> 2, c = ch & 3;
            br[i] = *(const bf16x8*)(W1t + m * F_IN + s * 32 + c * 8);
        }
    };
    auto writeAB = [&](int buf) {
        unsigned short* As = lds + buf * STAGE;
        unsigned short* Bs = As + 128 * PA;
        *(bf16x8*)(&As[am * PA + ac * 8]) = ar;
#pragma unroll
        for (int i = 0; i < 2; ++i) {
            int ch = tid + i * 512;
            int m = ch >> 2, c = ch & 3;
            *(bf16x8*)(&Bs[m * PB + c * 8]) = br[i];
        }
    };

    f32x4 acc[4][4] = {};
    loadAB(0);
    writeAB(0);
#pragma unroll
    for (int s = 0; s < S; ++s) {
        if (s + 1 < S) loadAB(s + 1);
        __syncthreads();
        const unsigned short* As = lds + (s & 1) * STAGE;
        const unsigned short* Bs = As + 128 * PA;
        bf16x8 af[4], bfr[4];
#pragma unroll
        for (int mt = 0; mt < 4; ++mt)
            af[mt] = *(const bf16x8*)(&As[(wm * 64 + mt * 16 + l15) * PA + q * 8]);
#pragma unroll
        for (int nt = 0; nt < 4; ++nt)
            bfr[nt] = *(const bf16x8*)(&Bs[(wn * 64 + nt * 16 + l15) * PB + q * 8]);
#pragma unroll
        for (int mt = 0; mt < 4; ++mt)
#pragma unroll
            for (int nt = 0; nt < 4; ++nt)
                acc[mt][nt] = __builtin_amdgcn_mfma_f32_16x16x32_bf16(
                    af[mt], bfr[nt], acc[mt][nt], 0, 0, 0);
        if (s + 1 < S) writeAB((s + 1) & 1);
    }
    __syncthreads();  // staging reads done; alias h1t

    // ---- Epilogue: BN partials + staged h1 tile ----
#pragma unroll
    for (int nt = 0; nt < 4; ++nt) {
        int col = wn * 64 + nt * 16 + l15;
        float b = b1[col];
        float s = 0.f, ss = 0.f;
#pragma unroll
        for (int mt = 0; mt < 4; ++mt) {
#pragma unroll
            for (int r = 0; r < 4; ++r) {
                long row = row0 + wm * 64 + mt * 16 + q * 4 + r;
                float v = acc[mt][nt][r] + b;
                if (row < M) { s += v; ss += v * v; }
                h1t[(wm * 64 + mt * 16 + q * 4 + r) * PH + col] = f2bf(v);
            }
        }
        s += __shfl_xor(s, 16, 64);  s += __shfl_xor(s, 32, 64);
        ss += __shfl_xor(ss, 16, 64); ss += __shfl_xor(ss, 32, 64);
        if (lane < 16) {
            long pr = (long)blockIdx.x * 2 + wm;
            partials[pr * 512 + col] = s;
            partials[pr * 512 + 256 + col] = ss;
        }
    }
    __syncthreads();
    {   // contiguous stores: thread t -> row t>>2, 64-col segment (t&3)*64
        int srow = tid >> 2, scol = (tid & 3) * 64;
        unsigned short* dst = h1 + (row0 + srow) * DIM_H + scol;
        const unsigned short* srcp = &h1t[srow * PH + scol];
#pragma unroll
        for (int j = 0; j < 8; ++j)
            *(bf16x8*)(dst + j * 8) = *(const bf16x8*)(srcp + j * 8);
    }
}

// ---------------- fused GEMM2 + GEMM3, 128x256 tile, 512 threads (unchanged) ----------------
__global__ __launch_bounds__(512, 4) void gemm23_kernel(
    const unsigned short* __restrict__ h1, const unsigned short* __restrict__ W2t,
    const float* __restrict__ b2,
    const float* __restrict__ scale, const float* __restrict__ shift,
    const unsigned short* __restrict__ Wlt, const float* __restrict__ blin,
    float* __restrict__ out, int M) {
    constexpr int S = 8;
    constexpr int PA = 40, PB = 40, PH = 264;
    constexpr int STAGE = 128 * PA + 256 * PB;
    __shared__ __align__(16) unsigned short lds[128 * PH];
    unsigned short* h2t = lds;

    int tid = threadIdx.x;
    int wave = tid >> 6, lane = tid & 63;
    int wm = wave >> 2, wn = wave & 3;
    int l15 = lane & 15, q = lane >> 4;
    long row0 = (long)blockIdx.x * 128;

    int am = tid >> 2, ac = tid & 3;
    bf16x8 ar, br[2];
    auto loadAB = [&](int s) {
        ar = *(const bf16x8*)(h1 + (row0 + am) * DIM_H + s * 32 + ac * 8);
#pragma unroll
        for (int i = 0; i < 2; ++i) {
            int ch = tid + i * 512;
            int m = ch >> 2, c = ch & 3;
            br[i] = *(const bf16x8*)(W2t + m * DIM_H + s * 32 + c * 8);
        }
    };
    auto writeAB = [&](int s, int buf) {
        unsigned short* As = lds + buf * STAGE;
        unsigned short* Bs = As + 128 * PA;
        {
            int kb = s * 32 + ac * 8;
            float4 sc0 = *(const float4*)(scale + kb);
            float4 sc1 = *(const float4*)(scale + kb + 4);
            float4 sh0 = *(const float4*)(shift + kb);
            float4 sh1 = *(const float4*)(shift + kb + 4);
            float scv[8] = {sc0.x, sc0.y, sc0.z, sc0.w, sc1.x, sc1.y, sc1.z, sc1.w};
            float shv[8] = {sh0.x, sh0.y, sh0.z, sh0.w, sh1.x, sh1.y, sh1.z, sh1.w};
            bf16x8 v = ar;
#pragma unroll
            for (int j = 0; j < 8; ++j) {
                float f = bf2f((unsigned short)v[j]);
                f = fmaxf(f * scv[j] + shv[j], 0.f);
                v[j] = (short)f2bf(f);
            }
            *(bf16x8*)(&As[am * PA + ac * 8]) = v;
        }
#pragma unroll
        for (int i = 0; i < 2; ++i) {
            int ch = tid + i * 512;
            int m = ch >> 2, c = ch & 3;
            *(bf16x8*)(&Bs[m * PB + c * 8]) = br[i];
        }
    };

    f32x4 acc[4][4] = {};
    loadAB(0);
    writeAB(0, 0);
#pragma unroll
    for (int s = 0; s < S; ++s) {
        if (s + 1 < S) loadAB(s + 1);
        __syncthreads();
        const unsigned short* As = lds + (s & 1) * STAGE;
        const unsigned short* Bs = As + 128 * PA;
        bf16x8 af[4], bfr[4];
#pragma unroll
        for (int mt = 0; mt < 4; ++mt)
            af[mt] = *(const bf16x8*)(&As[(wm * 64 + mt * 16 + l15) * PA + q * 8]);
#pragma unroll
        for (int nt = 0; nt < 4; ++nt)
            bfr[nt] = *(const bf16x8*)(&Bs[(wn * 64 + nt * 16 + l15) * PB + q * 8]);
#pragma unroll
        for (int mt = 0; mt < 4; ++mt)
#pragma unroll
            for (int nt = 0; nt < 4; ++nt)
                acc[mt][nt] = __builtin_amdgcn_mfma_f32_16x16x32_bf16(
                    af[mt], bfr[nt], acc[mt][nt], 0, 0, 0);
        if (s + 1 < S) writeAB(s + 1, (s + 1) & 1);
    }
    __syncthreads();

#pragma unroll
    for (int nt = 0; nt < 4; ++nt) {
        int colL = wn * 64 + nt * 16 + l15;
        float b = b2[colL];
#pragma unroll
        for (int mt = 0; mt < 4; ++mt)
#pragma unroll
            for (int r = 0; r < 4; ++r) {
                int rowL = wm * 64 + mt * 16 + q * 4 + r;
                h2t[rowL * PH + colL] = f2bf(fmaxf(acc[mt][nt][r] + b, 0.f));
            }
    }
    __syncthreads();

    f32x4 acc3[3] = {};
#pragma unroll
    for (int s = 0; s < 8; ++s) {
        bf16x8 a3 = *(const bf16x8*)(&h2t[(wave * 16 + l15) * PH + s * 32 + q * 8]);
#pragma unroll
        for (int nt = 0; nt < 3; ++nt) {
            bf16x8 b3 = *(const bf16x8*)(Wlt + (nt * 16 + l15) * 256 + s * 32 + q * 8);
            acc3[nt] = __builtin_amdgcn_mfma_f32_16x16x32_bf16(a3, b3, acc3[nt], 0, 0, 0);
        }
    }
#pragma unroll
    for (int nt = 0; nt < 3; ++nt) {
        int col = nt * 16 + l15;
        if (col < N_CLASSES) {
            float b = blin[col];
#pragma unroll
            for (int r = 0; r < 4; ++r) {
                long row = row0 + wave * 16 + q * 4 + r;
                if (row < M) out[row * N_CLASSES + col] = acc3[nt][r] + b;
            }
        }
    }
}

extern "C" void kernel_launch(void* const* d_in, const int* in_sizes, int n_in,
                              void* d_out, int out_size, void* d_ws, size_t ws_size,
                              hipStream_t stream) {
    const float* x     = (const float*)d_in[0];
    const int*   ei    = (const int*)d_in[1];
    const float* W1    = (const float*)d_in[2];
    const float* b1    = (const float*)d_in[3];
    const float* gamma = (const float*)d_in[4];
    const float* beta  = (const float*)d_in[5];
    const float* W2    = (const float*)d_in[6];
    const float* b2    = (const float*)d_in[7];
    const float* Wlin  = (const float*)d_in[8];
    const float* blin  = (const float*)d_in[9];
    float* out = (float*)d_out;

    int M  = in_sizes[0] / F_IN;  // 50000
    int nE = in_sizes[1] / 2;     // 600000
    const int* srcIdx = ei;
    const int* dstIdx = ei + nE;
    int nB = (M + 255) / 256;     // 196
    int g128 = (M + 127) / 128;   // 391 (GEMM1 & GEMM23 tiles)
    int XQ = M * 32;
    int ZQ = 2 * M / 4;

    unsigned short* h1bf  = (unsigned short*)d_ws;                     // M_PAD*256
    unsigned short* xb    = h1bf + (size_t)M_PAD * DIM_H;              // M_PAD*128
    unsigned short* A1bf  = xb + (size_t)M_PAD * F_IN;                 // M_PAD*128
    unsigned short* W1t   = A1bf + (size_t)M_PAD * F_IN;               // 256*128
    unsigned short* W2t   = W1t + DIM_H * F_IN;                        // 256*256
    unsigned short* Wlt   = W2t + DIM_H * DIM_H;                       // 64*256
    float*          partials = (float*)(Wlt + 64 * DIM_H);             // 2*g128*512
    float*          scale = partials + (size_t)800 * 512;              // 256
    float*          shift = scale + DIM_H;                             // 256
    int*            hist  = (int*)(shift + DIM_H);                     // M
    int*            cursor= hist + M;                                  // M (adjacent)
    int*            start = cursor + M;                                // M+1
    int*            blockSums = start + (M + 1);                       // 256
    int*            order = blockSums + 256;                           // nE

    int tB = 256;
    prep_kernel<<<(XQ + 114688 + ZQ + 255) / 256, 256, 0, stream>>>(
        x, xb, W1, W2, Wlin, W1t, W2t, Wlt, hist, XQ, ZQ);
    hist_kernel<<<(nE + tB - 1) / tB, tB, 0, stream>>>(dstIdx, hist, nE);
    scan_blocks_kernel<<<nB, 256, 0, stream>>>(hist, blockSums, M);
    scan_final_kernel<<<nB, 256, 0, stream>>>(hist, blockSums, start, M, nE);
    fill_kernel<<<(nE + tB - 1) / tB, tB, 0, stream>>>(srcIdx, dstIdx, start, cursor, order, nE);

    // standalone max-occupancy gather
    gather_kernel<<<(M + 7) / 8, 256, 0, stream>>>(xb, order, start, A1bf, M);
    // GEMM1 + BN partials
    gemm1_kernel<<<g128, 512, 0, stream>>>(A1bf, W1t, b1, h1bf, partials, M);
    bn_reduce_kernel<<<DIM_H, 256, 0, stream>>>(partials, 2 * g128, gamma, beta, scale, shift, M);
    // fused GEMM2 + GEMM3
    gemm23_kernel<<<g128, 512, 0, stream>>>(h1bf, W2t, b2, scale, shift, Wlt, blin, out, M);
}